// Round 4
// baseline (213.393 us; speedup 1.0000x reference)
//
#include <hip/hip_runtime.h>
#include <stdint.h>

#define DIM   384
#define NH    8
#define HD    48
#define NTOK  4096
#define KDIM  384
// 1/sqrt(48) * log2(e): q pre-scaled so softmax uses exp2 (v_exp_f32) directly
#define SCALEL2E 0.20823509610f

typedef float  f32x4   __attribute__((ext_vector_type(4)));
typedef float  f32x16  __attribute__((ext_vector_type(16)));
typedef __bf16 bf16x8  __attribute__((ext_vector_type(8)));

#if __has_builtin(__builtin_amdgcn_exp2f)
#define EXP2F(x) __builtin_amdgcn_exp2f(x)
#else
#define EXP2F(x) exp2f(x)
#endif

__device__ __forceinline__ unsigned short f2bf(float f) {
  union { float f; unsigned int u; } c; c.f = f;
  unsigned int r = (c.u + 0x7FFFu + ((c.u >> 16) & 1u)) >> 16;  // RNE
  return (unsigned short)r;
}
__device__ __forceinline__ float bf2f(unsigned short h) {
  union { unsigned int u; float f; } c; c.u = ((unsigned int)h) << 16;
  return c.f;
}

// ws layout (bytes):
//   x_bf @ 0        : 8192*384*2     = 6,291,456
//   w_bf @ 6291456  : 1152*384*2     =   884,736
//   qc   @ 7176192  : 2*8*4096*48*2  = 6,291,456   [b,h,n,48] bf16, scaled by SCALEL2E
//   kc   @ 13467648 : 6,291,456                     [b,h,n,48] bf16
//   v_t  @ 19759104 : 2*384*4096*2   = 6,291,456   [b,c,n] bf16
// total ~26.1 MB

// ---------------- prep: f32->bf16 conversions -------------------------------
__global__ void prep_kernel(const float* __restrict__ x, const float* __restrict__ w,
                            unsigned short* __restrict__ x_bf,
                            unsigned short* __restrict__ w_bf) {
  int tid = blockIdx.x * blockDim.x + threadIdx.x;
  int stride = gridDim.x * blockDim.x;
  for (int i = tid; i < 786432; i += stride) {
    float4 v = ((const float4*)x)[i];
    ushort4 o;
    o.x = f2bf(v.x); o.y = f2bf(v.y); o.z = f2bf(v.z); o.w = f2bf(v.w);
    ((ushort4*)x_bf)[i] = o;
  }
  for (int i = tid; i < 110592; i += stride) {
    float4 v = ((const float4*)w)[i];
    ushort4 o;
    o.x = f2bf(v.x); o.y = f2bf(v.y); o.z = f2bf(v.z); o.w = f2bf(v.w);
    ((ushort4*)w_bf)[i] = o;
  }
}

// ---------------- QKV GEMM: 8192 x 1152, K=384, 128x64 tiles ---------------
// Epilogue routes through ebuf LDS so all global stores are 16B vectors.
__global__ __launch_bounds__(256) void qkv_gemm(
    const unsigned short* __restrict__ A,    // x_bf [8192][384]
    const unsigned short* __restrict__ Bw,   // w_bf [1152][384]  (B^T)
    const float* __restrict__ bias,          // [1152]
    unsigned short* __restrict__ qc,
    unsigned short* __restrict__ kc,
    unsigned short* __restrict__ v_t) {
  __shared__ unsigned short ldsA[128 * 32];
  __shared__ unsigned short ldsB[64 * 32];
  __shared__ unsigned short ebuf[64 * 72];   // epilogue transpose buffer
  const int tid = threadIdx.x;
  const int wv = tid >> 6, ln = tid & 63;
  const int lrow = ln & 15, lq = ln >> 4;
  const int m0 = blockIdx.x * 128;
  const int n0 = blockIdx.y * 64;
  const int wm = (wv >> 1) * 64, wn = (wv & 1) * 32;

  f32x4 acc[4][2];
#pragma unroll
  for (int mi = 0; mi < 4; ++mi)
#pragma unroll
    for (int ni = 0; ni < 2; ++ni)
#pragma unroll
      for (int r = 0; r < 4; ++r) acc[mi][ni][r] = 0.f;

  for (int k0 = 0; k0 < KDIM; k0 += 32) {
    __syncthreads();
#pragma unroll
    for (int j = 0; j < 2; ++j) {
      int r16 = wv * 2 + j;
      const unsigned short* ga = A + (size_t)(m0 + r16 * 16 + (ln >> 2)) * KDIM
                                   + k0 + (ln & 3) * 8;
      __builtin_amdgcn_global_load_lds(
          (const __attribute__((address_space(1))) void*)ga,
          (__attribute__((address_space(3))) void*)&ldsA[r16 * 512], 16, 0, 0);
    }
    const unsigned short* gb = Bw + (size_t)(n0 + wv * 16 + (ln >> 2)) * KDIM
                                  + k0 + (ln & 3) * 8;
    __builtin_amdgcn_global_load_lds(
        (const __attribute__((address_space(1))) void*)gb,
        (__attribute__((address_space(3))) void*)&ldsB[wv * 512], 16, 0, 0);
    __syncthreads();
    bf16x8 af[4], bfv[2];
#pragma unroll
    for (int mi = 0; mi < 4; ++mi)
      af[mi] = *(const bf16x8*)&ldsA[(wm + mi * 16 + lrow) * 32 + lq * 8];
#pragma unroll
    for (int ni = 0; ni < 2; ++ni)
      bfv[ni] = *(const bf16x8*)&ldsB[(wn + ni * 16 + lrow) * 32 + lq * 8];
#pragma unroll
    for (int mi = 0; mi < 4; ++mi)
#pragma unroll
      for (int ni = 0; ni < 2; ++ni)
        acc[mi][ni] = __builtin_amdgcn_mfma_f32_16x16x32_bf16(
            af[mi], bfv[ni], acc[mi][ni], 0, 0, 0);
  }

  // ---- epilogue: C-tile half -> ebuf (bf16) -> 16B vector stores ----
  const int region = (n0 >= 768) ? 2 : (n0 >= 384 ? 1 : 0);   // q/k/v, block-uniform
  const float scl = (region == 0) ? SCALEL2E : 1.0f;
  const float bias0 = bias[n0 + wn + lrow];
  const float bias1 = bias[n0 + wn + 16 + lrow];

#pragma unroll
  for (int half = 0; half < 2; ++half) {
    __syncthreads();
    if ((wv >> 1) == half) {
#pragma unroll
      for (int mi = 0; mi < 4; ++mi)
#pragma unroll
        for (int ni = 0; ni < 2; ++ni)
#pragma unroll
          for (int r = 0; r < 4; ++r) {
            int row = mi * 16 + lq * 4 + r;        // 0..63 within half
            int col = wn + ni * 16 + lrow;         // 0..63
            float val = (acc[mi][ni][r] + (ni ? bias1 : bias0)) * scl;
            ebuf[row * 72 + col] = f2bf(val);
          }
    }
    __syncthreads();
    if (region < 2) {
      unsigned short* dst = (region == 0) ? qc : kc;
      const int obase = n0 - region * 384;
#pragma unroll
      for (int i = 0; i < 2; ++i) {
        int id = tid + i * 256;                    // 0..511 = 64 rows x 8 chunks
        int row = id >> 3, cc = id & 7;
        uint4 val = *(const uint4*)&ebuf[row * 72 + cc * 8];
        int nrow = m0 + half * 64 + row;
        int b = nrow >> 12, nn = nrow & 4095;
        int o = obase + cc * 8;
        int h = o / 48, d = o - h * 48;            // 8-chunk never straddles h
        *(uint4*)&dst[((size_t)(b * 8 + h) * NTOK + nn) * HD + d] = val;
      }
    } else {
#pragma unroll
      for (int i = 0; i < 2; ++i) {
        int id = tid + i * 256;                    // 0..511 = 64 cols x 8 row-chunks
        int col = id & 63, rc = id >> 6;
        int r0 = rc * 8;
        union { unsigned short s[8]; uint4 u; } pk;
#pragma unroll
        for (int j = 0; j < 8; ++j)
          pk.s[j] = ebuf[(r0 + j) * 72 + col];
        int nrow = m0 + half * 64 + r0;
        int b = nrow >> 12;
        int o = n0 - 768 + col;
        *(uint4*)&v_t[((size_t)(b * DIM + o)) * NTOK + (nrow & 4095)] = pk.u;
      }
    }
  }
}

// ---------------- flash attention + fused LePE epilogue --------------------
// block 256 = 2 kt-halves x 2 q-waves x 32 qrows; block = 1 image row (y=qb)
// x 1 head (48 channels). S^T = K*Q^T; V-LDS row 48 = 1.0 gives lsum free.
// Epilogue: lepe conv into Ol LDS, kh1 adds O*linv, kh0 stores (no RMW).
__global__ __launch_bounds__(256, 4) void attn_kernel(
    const unsigned short* __restrict__ qc,
    const unsigned short* __restrict__ kcg,
    const unsigned short* __restrict__ v_t,
    const float* __restrict__ lw, const float* __restrict__ lb,
    float* __restrict__ out) {
  __shared__ __align__(16) char smem[33280];
  unsigned short* Kl = (unsigned short*)smem;            // [2][64*64] swizzled
  unsigned short* Vl = (unsigned short*)(smem + 16384);  // [2][64*64] swizzled
  float* Lsum = (float*)(smem + 32768);                  // [2][64]
  float* Ol   = (float*)smem;                            // alias [64 px][48 ch]

  const int tid = threadIdx.x;
  const int wv = tid >> 6, ln = tid & 63;
  const int kh = wv >> 1;          // kt-half
  const int wq = wv & 1;           // qrow group
  const int l31 = ln & 31, hh = ln >> 5;
  const int th = tid & 127;        // thread id within half
  const int qb = blockIdx.x, bh = blockIdx.y;
  const int b = bh >> 3, hd = bh & 7;

  unsigned short* Kh = Kl + kh * 4096;
  unsigned short* Vh = Vl + kh * 4096;

  // staging offsets (loop-invariant), XOR-swizzled 8-chunk slots
  int kro[3], kgo[3], vro[3], vgo[3];
#pragma unroll
  for (int i = 0; i < 3; ++i) {
    int idx = th + i * 128;                // 0..383
    int r = idx / 6, cc = idx - r * 6;     // K: 64 rows x 6 chunks
    kro[i] = r * 64 + ((cc ^ (r & 7)) * 8);
    kgo[i] = r * 48 + cc * 8;
    int vd = idx >> 3, vc = idx & 7;       // V: 48 rows x 8 chunks
    vro[i] = vd * 64 + ((vc ^ (vd & 7)) * 8);
    vgo[i] = vd * 4096 + vc * 8;
  }

  // V ones-row (row 48): PV output col 48 = sum_k P = lsum. Never re-written.
  if (th < 8) {
    uint4 one4 = make_uint4(0x3F803F80u, 0x3F803F80u, 0x3F803F80u, 0x3F803F80u);
    *(uint4*)&Vh[3072 + th * 8] = one4;    // row 48 swizzle = identity (48&7==0)
  }

  // Q fragments: lane's own qrow, 3 hd-chunks of 16 (B-operand of K*Q^T)
  const int qrb_self = wq * 32 + l31;
  const unsigned short* qp = qc + ((size_t)bh * NTOK + qb * 64 + qrb_self) * HD + hh * 8;
  bf16x8 Qf[3];
#pragma unroll
  for (int hs = 0; hs < 3; ++hs)
    Qf[hs] = *(const bf16x8*)(qp + hs * 16);

  f32x16 Oacc[2];
#pragma unroll
  for (int dc = 0; dc < 2; ++dc)
#pragma unroll
    for (int r = 0; r < 16; ++r) Oacc[dc][r] = 0.f;

  const unsigned short* kbase = kcg + (size_t)bh * NTOK * HD;
  const unsigned short* vbase = v_t + ((size_t)b * DIM + hd * HD) * NTOK;

  for (int it = 0; it < 32; ++it) {
    const int kt = kh * 32 + it;
    __syncthreads();
    const unsigned short* kg = kbase + (size_t)kt * 64 * HD;
    const unsigned short* vg = vbase + kt * 64;
#pragma unroll
    for (int i = 0; i < 3; ++i) {
      *(uint4*)&Kh[kro[i]] = *(const uint4*)(kg + kgo[i]);
      *(uint4*)&Vh[vro[i]] = *(const uint4*)(vg + vgo[i]);
    }
    __syncthreads();

    // S^T = K * Q^T (two 32-key chunks x 3 K=16 steps); exp2; pack bf16 pairs
    unsigned int P32[16];
#pragma unroll
    for (int C = 0; C < 2; ++C) {
      f32x16 s;
#pragma unroll
      for (int r = 0; r < 16; ++r) s[r] = 0.f;
      const int krow = C * 32 + l31;
      const unsigned short* kr = &Kh[krow * 64];
      const int rx = krow & 7;
#pragma unroll
      for (int hs = 0; hs < 3; ++hs) {
        bf16x8 kf = *(const bf16x8*)&kr[((hs * 2 + hh) ^ rx) * 8];
        s = __builtin_amdgcn_mfma_f32_32x32x16_bf16(kf, Qf[hs], s, 0, 0, 0);
      }
#pragma unroll
      for (int t8 = 0; t8 < 8; ++t8) {
        float e0 = EXP2F(s[2 * t8]);
        float e1 = EXP2F(s[2 * t8 + 1]);
        P32[C * 8 + t8] = __builtin_amdgcn_perm(
            __float_as_uint(e1), __float_as_uint(e0), 0x07060302u);
      }
    }

    // O += P*V : single-shfl exchange (send what the partner needs)
#pragma unroll
    for (int s4 = 0; s4 < 4; ++s4) {
      const int o = (s4 >> 1) * 8 + (s4 & 1) * 4;
      unsigned int send1 = hh ? P32[o + 0] : P32[o + 2];
      unsigned int send2 = hh ? P32[o + 1] : P32[o + 3];
      unsigned int recv1 = (unsigned int)__shfl_xor((int)send1, 32, 64);
      unsigned int recv2 = (unsigned int)__shfl_xor((int)send2, 32, 64);
      union { unsigned int u[4]; bf16x8 v; } pa;
      pa.u[0] = hh ? recv1 : P32[o + 0];
      pa.u[1] = hh ? recv2 : P32[o + 1];
      pa.u[2] = hh ? P32[o + 2] : recv1;
      pa.u[3] = hh ? P32[o + 3] : recv2;
#pragma unroll
      for (int dc = 0; dc < 2; ++dc) {
        int vrow = dc * 32 + l31;          // row 48 = ones (lsum); 49-63 discarded
        bf16x8 vf = *(const bf16x8*)&Vh[vrow * 64 + (((s4 * 2 + hh) ^ (vrow & 7)) * 8)];
        Oacc[dc] = __builtin_amdgcn_mfma_f32_32x32x16_bf16(pa.v, vf, Oacc[dc], 0, 0, 0);
      }
    }
  }

  // ---- epilogue ----
  __syncthreads();
  // lsum (PV col 48) -> Lsum table
  if (l31 == 16) {
#pragma unroll
    for (int r = 0; r < 16; ++r) {
      int qrb = wq * 32 + (r & 3) + 8 * (r >> 2) + 4 * hh;
      Lsum[kh * 64 + qrb] = Oacc[1][r];
    }
  }
  // LePE conv into Ol[px][48]: thread t -> px = t&63, channels (t>>6)*12..+12
  {
    const int px = tid & 63;
    const int c0 = (tid >> 6) * 12;
    const int y = qb;
    const unsigned short* vpl = v_t + ((size_t)b * DIM + hd * HD) * NTOK;
    for (int cj = 0; cj < 12; ++cj) {
      int c = c0 + cj;
      const float* wp = lw + (size_t)(hd * HD + c) * 9;
      float a = lb[hd * HD + c];
      const unsigned short* pl = vpl + (size_t)c * NTOK + y * 64 + px;
#pragma unroll
      for (int dy = -1; dy <= 1; ++dy) {
        if ((unsigned)(y + dy) < 64u) {
#pragma unroll
          for (int dx = -1; dx <= 1; ++dx) {
            if ((unsigned)(px + dx) < 64u)
              a += wp[(dy + 1) * 3 + (dx + 1)] * bf2f(pl[dy * 64 + dx]);
          }
        }
      }
      Ol[px * 48 + c] = a;
    }
  }
  __syncthreads();
  if (kh == 1) {                 // add normalized O (half 1) into Ol
#pragma unroll
    for (int r = 0; r < 16; ++r) {
      int qrb = wq * 32 + (r & 3) + 8 * (r >> 2) + 4 * hh;
      float linv = 1.0f / (Lsum[qrb] + Lsum[64 + qrb]);
      Ol[qrb * 48 + l31] += Oacc[0][r] * linv;
      if (l31 < 16) Ol[qrb * 48 + 32 + l31] += Oacc[1][r] * linv;
    }
  }
  __syncthreads();
  if (kh == 0) {                 // final: lepe + O(half1) + O(half0), pure store
#pragma unroll
    for (int r = 0; r < 16; ++r) {
      int qrb = wq * 32 + (r & 3) + 8 * (r >> 2) + 4 * hh;
      float linv = 1.0f / (Lsum[qrb] + Lsum[64 + qrb]);
      float* op = out + ((size_t)(b * NTOK + qb * 64 + qrb)) * DIM + hd * HD;
      op[l31] = Ol[qrb * 48 + l31] + Oacc[0][r] * linv;
      if (l31 < 16) op[32 + l31] = Ol[qrb * 48 + 32 + l31] + Oacc[1][r] * linv;
    }
  }
}

// ---------------------------------------------------------------------------
extern "C" void kernel_launch(void* const* d_in, const int* in_sizes, int n_in,
                              void* d_out, int out_size, void* d_ws, size_t ws_size,
                              hipStream_t stream) {
  const float* x      = (const float*)d_in[0];
  const float* qkv_w  = (const float*)d_in[1];
  const float* qkv_b  = (const float*)d_in[2];
  const float* lepe_w = (const float*)d_in[3];
  const float* lepe_b = (const float*)d_in[4];

  char* ws = (char*)d_ws;
  unsigned short* x_bf = (unsigned short*)(ws);
  unsigned short* w_bf = (unsigned short*)(ws + 6291456);
  unsigned short* qcp  = (unsigned short*)(ws + 7176192);
  unsigned short* kcp  = (unsigned short*)(ws + 13467648);
  unsigned short* v_t  = (unsigned short*)(ws + 19759104);
  float* out = (float*)d_out;

  prep_kernel<<<1024, 256, 0, stream>>>(x, qkv_w, x_bf, w_bf);
  qkv_gemm<<<dim3(64, 18), 256, 0, stream>>>(x_bf, w_bf, qkv_b, qcp, kcp, v_t);
  attn_kernel<<<dim3(64, 16), 256, 0, stream>>>(qcp, kcp, v_t, lepe_w, lepe_b, out);
}

// Round 5
// 207.701 us; speedup vs baseline: 1.0274x; 1.0274x over previous
//
#include <hip/hip_runtime.h>
#include <stdint.h>

#define DIM   384
#define NH    8
#define HD    48
#define NTOK  4096
#define KDIM  384
// 1/sqrt(48) * log2(e): q pre-scaled so softmax uses exp2 (v_exp_f32) directly
#define SCALEL2E 0.20823509610f

typedef float  f32x4   __attribute__((ext_vector_type(4)));
typedef float  f32x16  __attribute__((ext_vector_type(16)));
typedef __bf16 bf16x8  __attribute__((ext_vector_type(8)));

#if __has_builtin(__builtin_amdgcn_exp2f)
#define EXP2F(x) __builtin_amdgcn_exp2f(x)
#else
#define EXP2F(x) exp2f(x)
#endif

__device__ __forceinline__ unsigned short f2bf(float f) {
  union { float f; unsigned int u; } c; c.f = f;
  unsigned int r = (c.u + 0x7FFFu + ((c.u >> 16) & 1u)) >> 16;  // RNE
  return (unsigned short)r;
}
__device__ __forceinline__ float bf2f(unsigned short h) {
  union { unsigned int u; float f; } c; c.u = ((unsigned int)h) << 16;
  return c.f;
}

// ws layout (bytes):
//   x_bf @ 0        : 8192*384*2     = 6,291,456
//   w_bf @ 6291456  : 1152*384*2     =   884,736
//   qc   @ 7176192  : 2*8*4096*48*2  = 6,291,456   [b,h,n,48] bf16, scaled by SCALEL2E
//   kc   @ 13467648 : 6,291,456                     [b,h,n,48] bf16
//   v_t  @ 19759104 : 2*384*4096*2   = 6,291,456   [b,c,n] bf16
// total ~26.1 MB  (kc overfetch by <=32B spills into v_t — allocated, harmless)

// ---------------- prep: f32->bf16 conversions -------------------------------
__global__ void prep_kernel(const float* __restrict__ x, const float* __restrict__ w,
                            unsigned short* __restrict__ x_bf,
                            unsigned short* __restrict__ w_bf) {
  int tid = blockIdx.x * blockDim.x + threadIdx.x;
  int stride = gridDim.x * blockDim.x;
  for (int i = tid; i < 786432; i += stride) {
    float4 v = ((const float4*)x)[i];
    ushort4 o;
    o.x = f2bf(v.x); o.y = f2bf(v.y); o.z = f2bf(v.z); o.w = f2bf(v.w);
    ((ushort4*)x_bf)[i] = o;
  }
  for (int i = tid; i < 110592; i += stride) {
    float4 v = ((const float4*)w)[i];
    ushort4 o;
    o.x = f2bf(v.x); o.y = f2bf(v.y); o.z = f2bf(v.z); o.w = f2bf(v.w);
    ((ushort4*)w_bf)[i] = o;
  }
}

// ---------------- QKV GEMM: 8192 x 1152, K=384, 128x64 tiles ---------------
// Epilogue routes through ebuf LDS so all global stores are 16B vectors.
__global__ __launch_bounds__(256) void qkv_gemm(
    const unsigned short* __restrict__ A,    // x_bf [8192][384]
    const unsigned short* __restrict__ Bw,   // w_bf [1152][384]  (B^T)
    const float* __restrict__ bias,          // [1152]
    unsigned short* __restrict__ qc,
    unsigned short* __restrict__ kc,
    unsigned short* __restrict__ v_t) {
  __shared__ unsigned short ldsA[128 * 32];
  __shared__ unsigned short ldsB[64 * 32];
  __shared__ unsigned short ebuf[64 * 72];   // epilogue transpose buffer
  const int tid = threadIdx.x;
  const int wv = tid >> 6, ln = tid & 63;
  const int lrow = ln & 15, lq = ln >> 4;
  const int m0 = blockIdx.x * 128;
  const int n0 = blockIdx.y * 64;
  const int wm = (wv >> 1) * 64, wn = (wv & 1) * 32;

  f32x4 acc[4][2];
#pragma unroll
  for (int mi = 0; mi < 4; ++mi)
#pragma unroll
    for (int ni = 0; ni < 2; ++ni)
#pragma unroll
      for (int r = 0; r < 4; ++r) acc[mi][ni][r] = 0.f;

  for (int k0 = 0; k0 < KDIM; k0 += 32) {
    __syncthreads();
#pragma unroll
    for (int j = 0; j < 2; ++j) {
      int r16 = wv * 2 + j;
      const unsigned short* ga = A + (size_t)(m0 + r16 * 16 + (ln >> 2)) * KDIM
                                   + k0 + (ln & 3) * 8;
      __builtin_amdgcn_global_load_lds(
          (const __attribute__((address_space(1))) void*)ga,
          (__attribute__((address_space(3))) void*)&ldsA[r16 * 512], 16, 0, 0);
    }
    const unsigned short* gb = Bw + (size_t)(n0 + wv * 16 + (ln >> 2)) * KDIM
                                  + k0 + (ln & 3) * 8;
    __builtin_amdgcn_global_load_lds(
        (const __attribute__((address_space(1))) void*)gb,
        (__attribute__((address_space(3))) void*)&ldsB[wv * 512], 16, 0, 0);
    __syncthreads();
    bf16x8 af[4], bfv[2];
#pragma unroll
    for (int mi = 0; mi < 4; ++mi)
      af[mi] = *(const bf16x8*)&ldsA[(wm + mi * 16 + lrow) * 32 + lq * 8];
#pragma unroll
    for (int ni = 0; ni < 2; ++ni)
      bfv[ni] = *(const bf16x8*)&ldsB[(wn + ni * 16 + lrow) * 32 + lq * 8];
#pragma unroll
    for (int mi = 0; mi < 4; ++mi)
#pragma unroll
      for (int ni = 0; ni < 2; ++ni)
        acc[mi][ni] = __builtin_amdgcn_mfma_f32_16x16x32_bf16(
            af[mi], bfv[ni], acc[mi][ni], 0, 0, 0);
  }

  // ---- epilogue: C-tile half -> ebuf (bf16) -> 16B vector stores ----
  const int region = (n0 >= 768) ? 2 : (n0 >= 384 ? 1 : 0);   // q/k/v, block-uniform
  const float scl = (region == 0) ? SCALEL2E : 1.0f;
  const float bias0 = bias[n0 + wn + lrow];
  const float bias1 = bias[n0 + wn + 16 + lrow];

#pragma unroll
  for (int half = 0; half < 2; ++half) {
    __syncthreads();
    if ((wv >> 1) == half) {
#pragma unroll
      for (int mi = 0; mi < 4; ++mi)
#pragma unroll
        for (int ni = 0; ni < 2; ++ni)
#pragma unroll
          for (int r = 0; r < 4; ++r) {
            int row = mi * 16 + lq * 4 + r;        // 0..63 within half
            int col = wn + ni * 16 + lrow;         // 0..63
            float val = (acc[mi][ni][r] + (ni ? bias1 : bias0)) * scl;
            ebuf[row * 72 + col] = f2bf(val);
          }
    }
    __syncthreads();
    if (region < 2) {
      unsigned short* dst = (region == 0) ? qc : kc;
      const int obase = n0 - region * 384;
#pragma unroll
      for (int i = 0; i < 2; ++i) {
        int id = tid + i * 256;                    // 0..511 = 64 rows x 8 chunks
        int row = id >> 3, cc = id & 7;
        uint4 val = *(const uint4*)&ebuf[row * 72 + cc * 8];
        int nrow = m0 + half * 64 + row;
        int b = nrow >> 12, nn = nrow & 4095;
        int o = obase + cc * 8;
        int h = o / 48, d = o - h * 48;            // 8-chunk never straddles h
        *(uint4*)&dst[((size_t)(b * 8 + h) * NTOK + nn) * HD + d] = val;
      }
    } else {
#pragma unroll
      for (int i = 0; i < 2; ++i) {
        int id = tid + i * 256;                    // 0..511 = 64 cols x 8 row-chunks
        int col = id & 63, rc = id >> 6;
        int r0 = rc * 8;
        union { unsigned short s[8]; uint4 u; } pk;
#pragma unroll
        for (int j = 0; j < 8; ++j)
          pk.s[j] = ebuf[(r0 + j) * 72 + col];
        int nrow = m0 + half * 64 + r0;
        int b = nrow >> 12;
        int o = n0 - 768 + col;
        *(uint4*)&v_t[((size_t)(b * DIM + o)) * NTOK + (nrow & 4095)] = pk.u;
      }
    }
  }
}

// ---------------- LePE: depthwise 3x3, coalesced output (writes out base) --
__global__ __launch_bounds__(256) void lepe_kernel(
    const unsigned short* __restrict__ v_t,
    const float* __restrict__ lw, const float* __restrict__ lb,
    float* __restrict__ out) {
  __shared__ __align__(16) unsigned short pl[16 * 648];
  const int cg = blockIdx.x;      // 0..23
  const int sy = blockIdx.y;      // 0..7
  const int b  = blockIdx.z;      // 0..1
  const int t = threadIdx.x;
  const int y0 = sy * 8;
#pragma unroll
  for (int i = 0; i < 5; ++i) {
    int id = t + i * 256;                      // 0..1279
    int c = id / 80, rem = id - c * 80;
    int row = rem >> 3, cx = rem & 7;
    int y = y0 - 1 + row;
    uint4 val = make_uint4(0u, 0u, 0u, 0u);
    if (y >= 0 && y < 64)
      val = *(const uint4*)(v_t + ((size_t)(b * DIM + cg * 16 + c)) * NTOK + y * 64 + cx * 8);
    *(uint4*)&pl[c * 648 + row * 64 + cx * 8] = val;
  }
  __syncthreads();
  const int c = t & 15, pg = t >> 4;
  const int cglob = cg * 16 + c;
  float w[9];
#pragma unroll
  for (int j = 0; j < 9; ++j) w[j] = lw[cglob * 9 + j];
  const float bias = lb[cglob];
  const unsigned short* base = &pl[c * 648];
  for (int i = 0; i < 32; ++i) {
    int p = pg * 32 + i;
    int lr = p >> 6, x = p & 63;
    float acc = bias;
#pragma unroll
    for (int ky = 0; ky < 3; ++ky)
#pragma unroll
      for (int kx = 0; kx < 3; ++kx) {
        int xx = x + kx - 1;
        if (xx >= 0 && xx < 64)
          acc += w[ky * 3 + kx] * bf2f(base[(lr + ky) * 64 + xx]);
      }
    out[((size_t)(b * NTOK + sy * 512 + p)) * DIM + cglob] = acc;
  }
}

// ---------------- flash attention: 2 Q-sets per wave (128 qrows/block) -----
// block 256 = 2 kt-halves x 2 q-waves; each wave owns TWO 32-row Q sets.
// Every K/V frag read and every staged tile serves 2x the work -> LDS traffic
// per qrow halves. K staged as 64x8 chunks (6 real + 2 overfetch, never read)
// so writes are phase-aligned conflict-free. V row 48 = ones -> lsum free.
__global__ __launch_bounds__(256, 2) void attn_kernel(
    const unsigned short* __restrict__ qc,
    const unsigned short* __restrict__ kcg,
    const unsigned short* __restrict__ v_t,
    float* __restrict__ out) {
  __shared__ __align__(16) char smem[33792];
  unsigned short* Kl = (unsigned short*)smem;            // [2][64*64] swizzled
  unsigned short* Vl = (unsigned short*)(smem + 16384);  // [2][64*64] swizzled
  float* Lsum = (float*)(smem + 32768);                  // [2][128]
  float* Ol   = (float*)smem;                            // alias [128][48] epilogue

  const int tid = threadIdx.x;
  const int wv = tid >> 6, ln = tid & 63;
  const int kh = wv >> 1;          // kt-half
  const int wq = wv & 1;           // qrow group within each set
  const int l31 = ln & 31, hh = ln >> 5;
  const int th = tid & 127;        // thread id within half
  const int qb = blockIdx.x;       // 0..31  (128 qrows each)
  const int bh = blockIdx.y;
  const int b = bh >> 3, hd = bh & 7;

  unsigned short* Kh = Kl + kh * 4096;
  unsigned short* Vh = Vl + kh * 4096;

  // staging offsets (loop-invariant). K: 64 rows x 8 chunks (2 overfetch),
  // phase-aligned: 8 consecutive lanes = one row = 8 distinct XOR slots.
  int kro[4], kgo[4], vro[3], vgo[3];
#pragma unroll
  for (int i = 0; i < 4; ++i) {
    int idx = th + i * 128;                // 0..511
    int r = idx >> 3, cc = idx & 7;
    kro[i] = r * 64 + ((cc ^ (r & 7)) * 8);
    kgo[i] = r * 48 + cc * 8;              // cc>=6 reads next row's head: never read back
  }
#pragma unroll
  for (int i = 0; i < 3; ++i) {
    int idx = th + i * 128;                // 0..383
    int vd = idx >> 3, vc = idx & 7;       // V: 48 rows x 8 chunks
    vro[i] = vd * 64 + ((vc ^ (vd & 7)) * 8);
    vgo[i] = vd * 4096 + vc * 8;
  }

  // V ones-row (row 48): PV output col 48 = sum_k P = lsum. Never re-written.
  if (th < 8) {
    uint4 one4 = make_uint4(0x3F803F80u, 0x3F803F80u, 0x3F803F80u, 0x3F803F80u);
    *(uint4*)&Vh[3072 + th * 8] = one4;    // row 48 swizzle = identity (48&7==0)
  }

  // Q fragments: 2 sets x (lane's own qrow, 3 hd-chunks of 16)
  bf16x8 Qf[2][3];
#pragma unroll
  for (int set = 0; set < 2; ++set) {
    const int qrow = qb * 128 + set * 64 + wq * 32 + l31;
    const unsigned short* qp = qc + ((size_t)bh * NTOK + qrow) * HD + hh * 8;
#pragma unroll
    for (int hs = 0; hs < 3; ++hs)
      Qf[set][hs] = *(const bf16x8*)(qp + hs * 16);
  }

  f32x16 Oacc[2][2];
#pragma unroll
  for (int set = 0; set < 2; ++set)
#pragma unroll
    for (int dc = 0; dc < 2; ++dc)
#pragma unroll
      for (int r = 0; r < 16; ++r) Oacc[set][dc][r] = 0.f;

  const unsigned short* kbase = kcg + (size_t)bh * NTOK * HD;
  const unsigned short* vbase = v_t + ((size_t)b * DIM + hd * HD) * NTOK;

  for (int it = 0; it < 32; ++it) {
    const int kt = kh * 32 + it;
    __syncthreads();
    const unsigned short* kg = kbase + (size_t)kt * 64 * HD;
    const unsigned short* vg = vbase + kt * 64;
#pragma unroll
    for (int i = 0; i < 4; ++i)
      *(uint4*)&Kh[kro[i]] = *(const uint4*)(kg + kgo[i]);
#pragma unroll
    for (int i = 0; i < 3; ++i)
      *(uint4*)&Vh[vro[i]] = *(const uint4*)(vg + vgo[i]);
    __syncthreads();

    // S^T = K * Q^T for both Q sets; each kf feeds 2 MFMAs
    unsigned int P32[2][16];
#pragma unroll
    for (int C = 0; C < 2; ++C) {
      f32x16 sA, sB;
#pragma unroll
      for (int r = 0; r < 16; ++r) { sA[r] = 0.f; sB[r] = 0.f; }
      const int krow = C * 32 + l31;
      const unsigned short* kr = &Kh[krow * 64];
      const int rx = krow & 7;
#pragma unroll
      for (int hs = 0; hs < 3; ++hs) {
        bf16x8 kf = *(const bf16x8*)&kr[((hs * 2 + hh) ^ rx) * 8];
        sA = __builtin_amdgcn_mfma_f32_32x32x16_bf16(kf, Qf[0][hs], sA, 0, 0, 0);
        sB = __builtin_amdgcn_mfma_f32_32x32x16_bf16(kf, Qf[1][hs], sB, 0, 0, 0);
      }
#pragma unroll
      for (int t8 = 0; t8 < 8; ++t8) {
        float a0 = EXP2F(sA[2 * t8]);
        float a1 = EXP2F(sA[2 * t8 + 1]);
        P32[0][C * 8 + t8] = __builtin_amdgcn_perm(
            __float_as_uint(a1), __float_as_uint(a0), 0x07060302u);
        float b0 = EXP2F(sB[2 * t8]);
        float b1 = EXP2F(sB[2 * t8 + 1]);
        P32[1][C * 8 + t8] = __builtin_amdgcn_perm(
            __float_as_uint(b1), __float_as_uint(b0), 0x07060302u);
      }
    }

    // O += P*V : each vf feeds 2 MFMAs (both sets)
#pragma unroll
    for (int s4 = 0; s4 < 4; ++s4) {
      bf16x8 vf[2];
#pragma unroll
      for (int dc = 0; dc < 2; ++dc) {
        int vrow = dc * 32 + l31;          // row 48 = ones (lsum); 49-63 discarded
        vf[dc] = *(const bf16x8*)&Vh[vrow * 64 + (((s4 * 2 + hh) ^ (vrow & 7)) * 8)];
      }
      const int o = (s4 >> 1) * 8 + (s4 & 1) * 4;
#pragma unroll
      for (int set = 0; set < 2; ++set) {
        unsigned int send1 = hh ? P32[set][o + 0] : P32[set][o + 2];
        unsigned int send2 = hh ? P32[set][o + 1] : P32[set][o + 3];
        unsigned int recv1 = (unsigned int)__shfl_xor((int)send1, 32, 64);
        unsigned int recv2 = (unsigned int)__shfl_xor((int)send2, 32, 64);
        union { unsigned int u[4]; bf16x8 v; } pa;
        pa.u[0] = hh ? recv1 : P32[set][o + 0];
        pa.u[1] = hh ? recv2 : P32[set][o + 1];
        pa.u[2] = hh ? P32[set][o + 2] : recv1;
        pa.u[3] = hh ? P32[set][o + 3] : recv2;
#pragma unroll
        for (int dc = 0; dc < 2; ++dc)
          Oacc[set][dc] = __builtin_amdgcn_mfma_f32_32x32x16_bf16(
              pa.v, vf[dc], Oacc[set][dc], 0, 0, 0);
      }
    }
  }

  // ---- epilogue: combine kt-halves through LDS, normalize, out += ----
  __syncthreads();
  if (l31 == 16) {
#pragma unroll
    for (int set = 0; set < 2; ++set)
#pragma unroll
      for (int r = 0; r < 16; ++r) {
        int qrb = set * 64 + wq * 32 + (r & 3) + 8 * (r >> 2) + 4 * hh;
        Lsum[kh * 128 + qrb] = Oacc[set][1][r];
      }
  }
  if (kh == 1) {
#pragma unroll
    for (int set = 0; set < 2; ++set)
#pragma unroll
      for (int r = 0; r < 16; ++r) {
        int qrb = set * 64 + wq * 32 + (r & 3) + 8 * (r >> 2) + 4 * hh;
        Ol[qrb * 48 + l31] = Oacc[set][0][r];
        if (l31 < 16) Ol[qrb * 48 + 32 + l31] = Oacc[set][1][r];
      }
  }
  __syncthreads();
  if (kh == 0) {
#pragma unroll
    for (int set = 0; set < 2; ++set)
#pragma unroll
      for (int r = 0; r < 16; ++r) {
        int qrb = set * 64 + wq * 32 + (r & 3) + 8 * (r >> 2) + 4 * hh;
        float linv = 1.0f / (Lsum[qrb] + Lsum[128 + qrb]);
        float* op = out + ((size_t)(b * NTOK + qb * 128 + qrb)) * DIM + hd * HD;
        op[l31] += (Oacc[set][0][r] + Ol[qrb * 48 + l31]) * linv;
        if (l31 < 16)
          op[32 + l31] += (Oacc[set][1][r] + Ol[qrb * 48 + 32 + l31]) * linv;
      }
  }
}

// ---------------------------------------------------------------------------
extern "C" void kernel_launch(void* const* d_in, const int* in_sizes, int n_in,
                              void* d_out, int out_size, void* d_ws, size_t ws_size,
                              hipStream_t stream) {
  const float* x      = (const float*)d_in[0];
  const float* qkv_w  = (const float*)d_in[1];
  const float* qkv_b  = (const float*)d_in[2];
  const float* lepe_w = (const float*)d_in[3];
  const float* lepe_b = (const float*)d_in[4];

  char* ws = (char*)d_ws;
  unsigned short* x_bf = (unsigned short*)(ws);
  unsigned short* w_bf = (unsigned short*)(ws + 6291456);
  unsigned short* qcp  = (unsigned short*)(ws + 7176192);
  unsigned short* kcp  = (unsigned short*)(ws + 13467648);
  unsigned short* v_t  = (unsigned short*)(ws + 19759104);
  float* out = (float*)d_out;

  prep_kernel<<<1024, 256, 0, stream>>>(x, qkv_w, x_bf, w_bf);
  qkv_gemm<<<dim3(64, 18), 256, 0, stream>>>(x_bf, w_bf, qkv_b, qcp, kcp, v_t);
  lepe_kernel<<<dim3(24, 8, 2), 256, 0, stream>>>(v_t, lepe_w, lepe_b, out);
  attn_kernel<<<dim3(32, 16), 256, 0, stream>>>(qcp, kcp, v_t, out);
}